// Round 12
// baseline (266.107 us; speedup 1.0000x reference)
//
#include <hip/hip_runtime.h>
#include <hip/hip_bf16.h>
#include <stdint.h>

typedef __bf16 bf16x8 __attribute__((ext_vector_type(8)));
typedef float f32x4 __attribute__((ext_vector_type(4)));

static __device__ __forceinline__ unsigned short f2bf(float x) {
    union { float f; unsigned u; } v; v.f = x;
    unsigned r = v.u + 0x7FFFu + ((v.u >> 16) & 1u);  // round-to-nearest-even
    return (unsigned short)(r >> 16);
}

static __device__ __forceinline__ void gload_lds16(const void* g, void* l) {
    auto gp = (const unsigned int __attribute__((address_space(1)))*)(reinterpret_cast<uintptr_t>(g));
    auto lp = (unsigned int __attribute__((address_space(3)))*)(reinterpret_cast<uintptr_t>(l));
    __builtin_amdgcn_global_load_lds(gp, lp, 16, 0, 0);
}

// ---------- Kernel A: attn = softmax(morphosyn @ W_affix), stored bf16, 16B-block XOR-swizzled ----------
__global__ void attn_kernel(const float* __restrict__ morphosyn,
                            const float* __restrict__ W,
                            unsigned short* __restrict__ attn_sw) {
    const int b = blockIdx.x;
    const int t = threadIdx.x;
    __shared__ float ms[128];
    __shared__ float red[4];
    if (t < 128) ms[t] = morphosyn[b * 128 + t];
    __syncthreads();
    float acc0 = 0.f, acc1 = 0.f;
    #pragma unroll 8
    for (int dm = 0; dm < 128; ++dm) {
        float m = ms[dm];
        acc0 = fmaf(m, W[dm * 512 + t], acc0);
        acc1 = fmaf(m, W[dm * 512 + t + 256], acc1);
    }
    const int lane = t & 63, wid = t >> 6;
    float mx = fmaxf(acc0, acc1);
    #pragma unroll
    for (int o = 32; o; o >>= 1) mx = fmaxf(mx, __shfl_xor(mx, o));
    if (lane == 0) red[wid] = mx;
    __syncthreads();
    mx = fmaxf(fmaxf(red[0], red[1]), fmaxf(red[2], red[3]));
    __syncthreads();
    float e0 = __expf(acc0 - mx), e1 = __expf(acc1 - mx);
    float sm = e0 + e1;
    #pragma unroll
    for (int o = 32; o; o >>= 1) sm += __shfl_xor(sm, o);
    if (lane == 0) red[wid] = sm;
    __syncthreads();
    sm = red[0] + red[1] + red[2] + red[3];
    const float inv = 1.0f / sm;
    const int swz = (b >> 2) & 3;
    #pragma unroll
    for (int h = 0; h < 2; ++h) {
        int v = t + h * 256;
        int ae = (v >> 5) * 32 + ((((v >> 3) & 3) ^ swz) << 3) + (v & 7);
        attn_sw[b * 512 + ae] = f2bf((h ? e1 : e0) * inv);
    }
}

// ---------- Kernel B: wC[b,n] = cumsum_n( sum_ijk a_i b_j f_k softmax(logits[ijbk,:]) ) ----------
__global__ void wc_kernel(const float* __restrict__ logits,
                          const float* __restrict__ alpha,
                          const float* __restrict__ beta,
                          const float* __restrict__ phi,
                          float* __restrict__ wC) {
    const int b = blockIdx.x;
    const int t = threadIdx.x;
    const int lane = t & 63, wid = t >> 6;
    __shared__ float part[4][256];
    __shared__ float wsum[4];

    float a0 = alpha[0], a1 = alpha[1];
    float am = fmaxf(a0, a1);
    float ea0 = __expf(a0 - am), ea1 = __expf(a1 - am);
    float as = ea0 + ea1;
    float b0 = beta[0], b1 = beta[1];
    float bm = fmaxf(b0, b1);
    float eb0 = __expf(b0 - bm), eb1 = __expf(b1 - bm);
    float bs = eb0 + eb1;
    float p[5];
    float pm = -1e30f;
    #pragma unroll
    for (int k = 0; k < 5; ++k) { p[k] = phi[k]; pm = fmaxf(pm, p[k]); }
    float ps = 0.f;
    #pragma unroll
    for (int k = 0; k < 5; ++k) { p[k] = __expf(p[k] - pm); ps += p[k]; }
    const float wa[2] = {ea0 / as, ea1 / as}, wb[2] = {eb0 / bs, eb1 / bs};

    f32x4 accv = {0.f, 0.f, 0.f, 0.f};
    #pragma unroll
    for (int s5 = 0; s5 < 5; ++s5) {
        int sl = wid * 5 + s5;
        int i = sl >= 10;
        int j = (sl / 5) & 1;
        int k = sl - (sl / 5) * 5;
        const float* base = logits + ((size_t)(((i * 2 + j) * 1024 + b) * 5 + k)) * 256;
        f32x4 x = *(const f32x4*)(base + lane * 4);
        float mx = fmaxf(fmaxf(x[0], x[1]), fmaxf(x[2], x[3]));
        #pragma unroll
        for (int o = 32; o; o >>= 1) mx = fmaxf(mx, __shfl_xor(mx, o));
        f32x4 e;
        float sm = 0.f;
        #pragma unroll
        for (int r = 0; r < 4; ++r) { e[r] = __expf(x[r] - mx); sm += e[r]; }
        #pragma unroll
        for (int o = 32; o; o >>= 1) sm += __shfl_xor(sm, o);
        float w = wa[i] * wb[j] * (p[k] / ps) / sm;
        #pragma unroll
        for (int r = 0; r < 4; ++r) accv[r] += w * e[r];
    }
    *(f32x4*)&part[wid][lane * 4] = accv;
    __syncthreads();
    float v = part[0][t] + part[1][t] + part[2][t] + part[3][t];
    #pragma unroll
    for (int o = 1; o < 64; o <<= 1) {
        float u = __shfl_up(v, o);
        if (lane >= o) v += u;
    }
    if (lane == 63) wsum[wid] = v;
    __syncthreads();
    float offv = 0.f;
    for (int w2 = 0; w2 < wid; ++w2) offv += wsum[w2];
    wC[b * 256 + t] = v + offv;
}

// ---------- Kernel T: vocab f32 [v][n'] -> bf16 Bt[n'][v], 16B-block XOR-swizzled per row ----------
__global__ void conv_kernel(const float* __restrict__ vocab, unsigned short* __restrict__ Bt) {
    const int n0 = blockIdx.x * 16;
    const int t = threadIdx.x;
    __shared__ unsigned int T[16 * 256];  // [n][v/2] dwords
    #pragma unroll
    for (int it = 0; it < 4; ++it) {
        int p = it * 256 + t;
        int v = (p >> 2) * 2;
        int col4 = p & 3;
        const float* g0 = vocab + (size_t)v * 65536 + n0 + col4 * 4;
        float4 a = *(const float4*)g0;
        float4 c = *(const float4*)(g0 + 65536);
        #pragma unroll
        for (int j = 0; j < 4; ++j) {
            int n = col4 * 4 + j;
            unsigned d = (unsigned)f2bf((&a.x)[j]) | ((unsigned)f2bf((&c.x)[j]) << 16);
            T[n * 256 + (v >> 1)] = d;
        }
    }
    __syncthreads();
    #pragma unroll
    for (int it = 0; it < 4; ++it) {
        int qq = it * 256 + t;
        int r = qq >> 6, c = qq & 63;
        int swz = ((n0 + r) >> 2) & 3;
        int dc = (c & ~3) | ((c & 3) ^ swz);
        uint4 d = *(const uint4*)(&T[r * 256 + c * 4]);
        *(uint4*)(Bt + (size_t)(n0 + r) * 512 + dc * 8) = d;
    }
}

// ---------- Kernel C (fast): 256x128 tile, BK=32, 8 waves (4x2), 3-buf ring ----------
// R11 K-loop (race-free, verified absmax 0.0156) + epilogue MLP fix: launch_bounds(512,2)
// lifts the 64-VGPR cap (LDS already limits to 2 blocks/CU, so no occupancy cost) and each
// pass's stem/wC loads are issued BEFORE the bounce barriers so HBM latency hides under them.
__global__ __launch_bounds__(512, 2) void gemm_kernel(
        const unsigned short* __restrict__ attn_sw,
        const unsigned short* __restrict__ Bt,
        const float* __restrict__ stem,
        const float* __restrict__ wC,
        float* __restrict__ out) {
    // 2048 blocks: xcd = bid&7; per XCD: 64 n-panels x 4 m-tiles, m fastest (panel L2 reuse).
    const int bid = blockIdx.x;
    const int xcd = bid & 7, s = bid >> 3;          // s: 0..255
    const int m0 = (s & 3) << 8;                    // 4 m-tiles of 256 rows
    const int n0 = ((xcd << 6) + (s >> 2)) << 7;    // 512 n-panels of 128 cols
    const int t = threadIdx.x;                      // 0..511
    const int lane = t & 63, wid = t >> 6;          // 8 waves: wr 0..3 (64 rows), wcn 0..1 (64 cols)
    const int wr = wid >> 1, wcn = wid & 1;
    const int q = lane >> 4, rl = lane & 15;
    const int soff = ((q ^ ((rl >> 2) & 3)) << 4);  // XOR-swizzle byte offset (matches writers)

    __shared__ __align__(16) unsigned short ldsb[36864];  // 72KB: 3 bufs x (A 16KB + B 8KB)

    f32x4 acc[4][4];
    const f32x4 z = {0.f, 0.f, 0.f, 0.f};
    #pragma unroll
    for (int i = 0; i < 4; ++i)
        #pragma unroll
        for (int j = 0; j < 4; ++j) acc[i][j] = z;

    // per-thread staging sources (pre-swizzled in ws -> linear LDS dest is correct)
    const unsigned short* a_src = attn_sw + (size_t)(m0 + (t >> 2)) * 512 + (t & 3) * 8;
    const unsigned short* b_src = Bt + (size_t)(n0 + (t >> 2)) * 512 + (t & 3) * 8;

// 3 global_load_lds per thread (2 A + 1 B); buf ring = kt % 3
#define STAGE(kt) do { \
    unsigned short* dst_ = ldsb + ((kt) % 3) * 12288; \
    const int ko_ = (kt) * 32; \
    gload_lds16(a_src + ko_, dst_ + t * 8); \
    gload_lds16(a_src + 65536 + ko_, dst_ + 4096 + t * 8); \
    gload_lds16(b_src + ko_, dst_ + 8192 + t * 8); \
} while (0)

// One K-step, ONE barrier. Order: wait stage(kt) landed -> barrier (all waves done
// reading buf((kt+2)%3) in compute(kt-1)) -> issue STAGE(kt+2) -> compute(kt).
#define KSTEP(kt, STG, VMSTR) do { \
    asm volatile("s_waitcnt vmcnt(" VMSTR ")" ::: "memory"); \
    __builtin_amdgcn_s_barrier(); \
    __builtin_amdgcn_sched_barrier(0); \
    if (STG) STAGE((kt) + 2); \
    const char* abase_ = (const char*)(ldsb + ((kt) % 3) * 12288); \
    const char* bbase_ = abase_ + 16384; \
    bf16x8 af_[4], bfv_[4]; \
    _Pragma("unroll") \
    for (int f_ = 0; f_ < 4; ++f_) \
        af_[f_] = *(const bf16x8*)(abase_ + (wr * 64 + f_ * 16 + rl) * 64 + soff); \
    _Pragma("unroll") \
    for (int j_ = 0; j_ < 4; ++j_) \
        bfv_[j_] = *(const bf16x8*)(bbase_ + (wcn * 64 + j_ * 16 + rl) * 64 + soff); \
    __builtin_amdgcn_s_setprio(1); \
    _Pragma("unroll") \
    for (int fm_ = 0; fm_ < 4; ++fm_) \
        _Pragma("unroll") \
        for (int j_ = 0; j_ < 4; ++j_) \
            acc[fm_][j_] = __builtin_amdgcn_mfma_f32_16x16x32_bf16( \
                af_[fm_], bfv_[j_], acc[fm_][j_], 0, 0, 0); \
    __builtin_amdgcn_s_setprio(0); \
    __builtin_amdgcn_sched_barrier(0); \
} while (0)

    STAGE(0); STAGE(1);
    KSTEP(0, 1, "3");  KSTEP(1, 1, "3");  KSTEP(2, 1, "3");  KSTEP(3, 1, "3");
    KSTEP(4, 1, "3");  KSTEP(5, 1, "3");  KSTEP(6, 1, "3");  KSTEP(7, 1, "3");
    KSTEP(8, 1, "3");  KSTEP(9, 1, "3");  KSTEP(10, 1, "3"); KSTEP(11, 1, "3");
    KSTEP(12, 1, "3"); KSTEP(13, 1, "3"); KSTEP(14, 0, "3"); KSTEP(15, 0, "0");
#undef STAGE
#undef KSTEP

    // ---- epilogue: 4 passes of 64 rows; per pass: issue stem/wC loads EARLY, then
    // acc -> LDS [64][132] bounce (hides the HBM latency), then f32x4 RMW + store. ----
    float* cs = (float*)ldsb;
    #pragma unroll
    for (int sb = 0; sb < 4; ++sb) {
        // early-issued global loads for this pass (independent of LDS)
        f32x4 sv[4], wv[4];
        #pragma unroll
        for (int i2 = 0; i2 < 4; ++i2) {
            int row = i2 * 16 + (t >> 5);
            int b = m0 + sb * 64 + row;
            size_t gb = (size_t)b * 65536 + (size_t)n0 + (t & 31) * 4;
            sv[i2] = *(const f32x4*)&stem[gb];
            wv[i2] = *(const f32x4*)&wC[((size_t)b << 8) + (n0 & 255) + (t & 31) * 4];
        }
        __syncthreads();   // K-loop LDS done (sb=0) / previous pass cv reads done (sb>0)
        if (wr == sb) {
            #pragma unroll
            for (int fm = 0; fm < 4; ++fm) {
                #pragma unroll
                for (int n = 0; n < 4; ++n) {
                    int c = wcn * 64 + n * 16 + rl;
                    #pragma unroll
                    for (int i = 0; i < 4; ++i)
                        cs[(fm * 16 + q * 4 + i) * 132 + c] = acc[fm][n][i];
                }
            }
        }
        __syncthreads();
        #pragma unroll
        for (int i2 = 0; i2 < 4; ++i2) {
            int row = i2 * 16 + (t >> 5);
            int b = m0 + sb * 64 + row;
            size_t gb = (size_t)b * 65536 + (size_t)n0 + (t & 31) * 4;
            f32x4 cv = *(const f32x4*)&cs[row * 132 + (t & 31) * 4];
            f32x4 ov;
            #pragma unroll
            for (int jj = 0; jj < 4; ++jj)
                ov[jj] = sv[i2][jj] + (cv[jj] - sv[i2][jj]) * wv[i2][jj];
            *(f32x4*)&out[gb] = ov;
        }
    }
}

// ---------- Kernel C (fallback, ws too small): in-kernel convert+transpose, 128^2 ----------
__global__ void gemm_fb(const unsigned short* __restrict__ attn_sw,
                        const float* __restrict__ vocab,
                        const float* __restrict__ stem,
                        const float* __restrict__ wC,
                        float* __restrict__ out) {
    const int tile_m = blockIdx.x & 7;
    const int tile_n = blockIdx.x >> 3;
    const int m0 = tile_m << 7;
    const int n0 = tile_n << 7;
    const int t = threadIdx.x;
    const int lane = t & 63;
    const int wv = t >> 6;
    const int wm = wv >> 1, wn = wv & 1;

    __shared__ unsigned short Asl[128 * 32];
    __shared__ unsigned short Bsl[128 * 32];

    f32x4 acc[4][4];
    const f32x4 z = {0.f, 0.f, 0.f, 0.f};
    #pragma unroll
    for (int i = 0; i < 4; ++i)
        #pragma unroll
        for (int j = 0; j < 4; ++j) acc[i][j] = z;

    const unsigned short* a_base = attn_sw + ((size_t)m0 << 9);
    const int q = lane >> 4;
    const int rl = lane & 15;

    for (int ks = 0; ks < 16; ++ks) {
        #pragma unroll
        for (int it = 0; it < 2; ++it) {
            int idx = it * 256 + t;
            int r = idx >> 2, blk = idx & 3;
            gload_lds16(a_base + r * 512 + ks * 32 + blk * 8, Asl + idx * 8);
        }
        #pragma unroll
        for (int it = 0; it < 2; ++it) {
            int lin = it * 256 + t;
            int pair = lin >> 5;
            int chunk = lin & 31;
            int k = pair * 2;
            const float* g0 = vocab + (size_t)(ks * 32 + k) * 65536 + n0 + chunk * 4;
            float4 v0 = *(const float4*)g0;
            float4 v1 = *(const float4*)(g0 + 65536);
            #pragma unroll
            for (int j = 0; j < 4; ++j) {
                int n = chunk * 4 + j;
                unsigned d = (unsigned)f2bf((&v0.x)[j]) | ((unsigned)f2bf((&v1.x)[j]) << 16);
                int ae = n * 32 + ((((k >> 3) ^ ((n >> 2) & 3))) << 3) + (k & 7);
                *(unsigned*)((char*)Bsl + ae * 2) = d;
            }
        }
        __syncthreads();
        bf16x8 af[4], bfr[4];
        #pragma unroll
        for (int f = 0; f < 4; ++f) {
            int r = wm * 64 + f * 16 + rl;
            af[f] = *(const bf16x8*)((const char*)Asl + r * 64 + ((q ^ ((r >> 2) & 3)) << 4));
            int c = wn * 64 + f * 16 + rl;
            bfr[f] = *(const bf16x8*)((const char*)Bsl + c * 64 + ((q ^ ((c >> 2) & 3)) << 4));
        }
        __syncthreads();
        #pragma unroll
        for (int fm = 0; fm < 4; ++fm)
            #pragma unroll
            for (int fn = 0; fn < 4; ++fn)
                acc[fm][fn] = __builtin_amdgcn_mfma_f32_16x16x32_bf16(af[fm], bfr[fn], acc[fm][fn], 0, 0, 0);
    }

    #pragma unroll
    for (int fm = 0; fm < 4; ++fm) {
        int rbase = m0 + wm * 64 + fm * 16 + ((lane >> 4) << 2);
        #pragma unroll
        for (int fn = 0; fn < 4; ++fn) {
            int c = n0 + wn * 64 + fn * 16 + (lane & 15);
            #pragma unroll
            for (int i = 0; i < 4; ++i) {
                int b = rbase + i;
                float w = wC[(b << 8) + (c & 255)];
                size_t o = ((size_t)b << 16) + (size_t)c;
                float sv = stem[o];
                out[o] = sv + (acc[fm][fn][i] - sv) * w;
            }
        }
    }
}

extern "C" void kernel_launch(void* const* d_in, const int* in_sizes, int n_in,
                              void* d_out, int out_size, void* d_ws, size_t ws_size,
                              hipStream_t stream) {
    const float* stem    = (const float*)d_in[0];
    const float* morpho  = (const float*)d_in[1];
    const float* logits  = (const float*)d_in[2];
    const float* W       = (const float*)d_in[3];
    const float* vocab   = (const float*)d_in[4];
    const float* alpha   = (const float*)d_in[5];
    const float* beta    = (const float*)d_in[6];
    const float* phi     = (const float*)d_in[7];
    float* out = (float*)d_out;

    unsigned short* attn_sw = (unsigned short*)d_ws;                 // 1 MB
    float* wC = (float*)((char*)d_ws + (1 << 20));                   // 1 MB
    unsigned short* Bt = (unsigned short*)((char*)d_ws + (2 << 20)); // 64 MB

    const size_t need = (size_t)(2 << 20) + (size_t)64 * 1024 * 1024;

    attn_kernel<<<1024, 256, 0, stream>>>(morpho, W, attn_sw);
    wc_kernel<<<1024, 256, 0, stream>>>(logits, alpha, beta, phi, wC);
    if (ws_size >= need) {
        conv_kernel<<<4096, 256, 0, stream>>>(vocab, Bt);
        gemm_kernel<<<2048, 512, 0, stream>>>(attn_sw, Bt, stem, wC, out);
    } else {
        gemm_fb<<<4096, 256, 0, stream>>>(attn_sw, vocab, stem, wC, out);
    }
}

// Round 13
// 240.117 us; speedup vs baseline: 1.1082x; 1.1082x over previous
//
#include <hip/hip_runtime.h>
#include <hip/hip_bf16.h>
#include <stdint.h>

typedef __bf16 bf16x8 __attribute__((ext_vector_type(8)));
typedef float f32x4 __attribute__((ext_vector_type(4)));

static __device__ __forceinline__ unsigned short f2bf(float x) {
    union { float f; unsigned u; } v; v.f = x;
    unsigned r = v.u + 0x7FFFu + ((v.u >> 16) & 1u);  // round-to-nearest-even
    return (unsigned short)(r >> 16);
}

static __device__ __forceinline__ void gload_lds16(const void* g, void* l) {
    auto gp = (const unsigned int __attribute__((address_space(1)))*)(reinterpret_cast<uintptr_t>(g));
    auto lp = (unsigned int __attribute__((address_space(3)))*)(reinterpret_cast<uintptr_t>(l));
    __builtin_amdgcn_global_load_lds(gp, lp, 16, 0, 0);
}

// ---------- Fused pre-pass: conv (blocks 0..4095) | wc (4096..5119) | attn (5120..6143) ----------
// Three independent memory-bound producers share one dispatch so their HBM/L3 streams overlap
// instead of running serially with launch/drain gaps between them.
__global__ __launch_bounds__(256, 4) void prepass_kernel(
        const float* __restrict__ vocab, unsigned short* __restrict__ Bt,
        const float* __restrict__ logits, const float* __restrict__ alpha,
        const float* __restrict__ beta, const float* __restrict__ phi,
        float* __restrict__ wC,
        const float* __restrict__ morphosyn, const float* __restrict__ W,
        unsigned short* __restrict__ attn_sw) {
    const int bid = blockIdx.x;
    const int t = threadIdx.x;
    const int lane = t & 63, wid = t >> 6;

    if (bid < 4096) {
        // ---- conv: vocab f32 [v][n'] -> bf16 Bt[n'][v], 16B-block XOR-swizzled per row ----
        const int n0 = bid * 16;
        __shared__ unsigned int T[16 * 256];  // [n][v/2] dwords
        #pragma unroll
        for (int it = 0; it < 4; ++it) {
            int p = it * 256 + t;
            int v = (p >> 2) * 2;
            int col4 = p & 3;
            const float* g0 = vocab + (size_t)v * 65536 + n0 + col4 * 4;
            float4 a = *(const float4*)g0;
            float4 c = *(const float4*)(g0 + 65536);
            #pragma unroll
            for (int j = 0; j < 4; ++j) {
                int n = col4 * 4 + j;
                unsigned d = (unsigned)f2bf((&a.x)[j]) | ((unsigned)f2bf((&c.x)[j]) << 16);
                T[n * 256 + (v >> 1)] = d;
            }
        }
        __syncthreads();
        #pragma unroll
        for (int it = 0; it < 4; ++it) {
            int qq = it * 256 + t;
            int r = qq >> 6, c = qq & 63;
            int swz = ((n0 + r) >> 2) & 3;
            int dc = (c & ~3) | ((c & 3) ^ swz);
            uint4 d = *(const uint4*)(&T[r * 256 + c * 4]);
            *(uint4*)(Bt + (size_t)(n0 + r) * 512 + dc * 8) = d;
        }
    } else if (bid < 5120) {
        // ---- wc: wC[b,n] = cumsum_n( sum_ijk a_i b_j f_k softmax(logits[ijbk,:]) ) ----
        const int b = bid - 4096;
        __shared__ float part[4][256];
        __shared__ float wsum[4];

        float a0 = alpha[0], a1 = alpha[1];
        float am = fmaxf(a0, a1);
        float ea0 = __expf(a0 - am), ea1 = __expf(a1 - am);
        float as = ea0 + ea1;
        float b0 = beta[0], b1 = beta[1];
        float bm = fmaxf(b0, b1);
        float eb0 = __expf(b0 - bm), eb1 = __expf(b1 - bm);
        float bs = eb0 + eb1;
        float p[5];
        float pm = -1e30f;
        #pragma unroll
        for (int k = 0; k < 5; ++k) { p[k] = phi[k]; pm = fmaxf(pm, p[k]); }
        float ps = 0.f;
        #pragma unroll
        for (int k = 0; k < 5; ++k) { p[k] = __expf(p[k] - pm); ps += p[k]; }
        const float wa[2] = {ea0 / as, ea1 / as}, wb[2] = {eb0 / bs, eb1 / bs};

        f32x4 accv = {0.f, 0.f, 0.f, 0.f};
        #pragma unroll
        for (int s5 = 0; s5 < 5; ++s5) {
            int sl = wid * 5 + s5;
            int i = sl >= 10;
            int j = (sl / 5) & 1;
            int k = sl - (sl / 5) * 5;
            const float* base = logits + ((size_t)(((i * 2 + j) * 1024 + b) * 5 + k)) * 256;
            f32x4 x = *(const f32x4*)(base + lane * 4);
            float mx = fmaxf(fmaxf(x[0], x[1]), fmaxf(x[2], x[3]));
            #pragma unroll
            for (int o = 32; o; o >>= 1) mx = fmaxf(mx, __shfl_xor(mx, o));
            f32x4 e;
            float sm = 0.f;
            #pragma unroll
            for (int r = 0; r < 4; ++r) { e[r] = __expf(x[r] - mx); sm += e[r]; }
            #pragma unroll
            for (int o = 32; o; o >>= 1) sm += __shfl_xor(sm, o);
            float w = wa[i] * wb[j] * (p[k] / ps) / sm;
            #pragma unroll
            for (int r = 0; r < 4; ++r) accv[r] += w * e[r];
        }
        *(f32x4*)&part[wid][lane * 4] = accv;
        __syncthreads();
        float v = part[0][t] + part[1][t] + part[2][t] + part[3][t];
        #pragma unroll
        for (int o = 1; o < 64; o <<= 1) {
            float u = __shfl_up(v, o);
            if (lane >= o) v += u;
        }
        if (lane == 63) wsum[wid] = v;
        __syncthreads();
        float offv = 0.f;
        for (int w2 = 0; w2 < wid; ++w2) offv += wsum[w2];
        wC[b * 256 + t] = v + offv;
    } else {
        // ---- attn: softmax(morphosyn @ W_affix), stored bf16, 16B-block XOR-swizzled ----
        const int b = bid - 5120;
        __shared__ float ms[128];
        __shared__ float red[4];
        if (t < 128) ms[t] = morphosyn[b * 128 + t];
        __syncthreads();
        float acc0 = 0.f, acc1 = 0.f;
        #pragma unroll 8
        for (int dm = 0; dm < 128; ++dm) {
            float m = ms[dm];
            acc0 = fmaf(m, W[dm * 512 + t], acc0);
            acc1 = fmaf(m, W[dm * 512 + t + 256], acc1);
        }
        float mx = fmaxf(acc0, acc1);
        #pragma unroll
        for (int o = 32; o; o >>= 1) mx = fmaxf(mx, __shfl_xor(mx, o));
        if (lane == 0) red[wid] = mx;
        __syncthreads();
        mx = fmaxf(fmaxf(red[0], red[1]), fmaxf(red[2], red[3]));
        __syncthreads();
        float e0 = __expf(acc0 - mx), e1 = __expf(acc1 - mx);
        float sm = e0 + e1;
        #pragma unroll
        for (int o = 32; o; o >>= 1) sm += __shfl_xor(sm, o);
        if (lane == 0) red[wid] = sm;
        __syncthreads();
        sm = red[0] + red[1] + red[2] + red[3];
        const float inv = 1.0f / sm;
        const int swz = (b >> 2) & 3;
        #pragma unroll
        for (int h = 0; h < 2; ++h) {
            int v = t + h * 256;
            int ae = (v >> 5) * 32 + ((((v >> 3) & 3) ^ swz) << 3) + (v & 7);
            attn_sw[b * 512 + ae] = f2bf((h ? e1 : e0) * inv);
        }
    }
}

// ---------- Kernel C (fast): 256x128 tile, BK=32, 8 waves (4x2), 3-buf ring — R11 exact ----------
// launch_bounds(512,4): the 64-VGPR cap keeps wave total at 64+64(AGPR)=128 regs -> 4 waves/SIMD
// -> 16 waves/CU -> 2 blocks resident (R12's 68-VGPR build dropped to 1 block/CU: 132>128).
__global__ __launch_bounds__(512, 4) void gemm_kernel(
        const unsigned short* __restrict__ attn_sw,
        const unsigned short* __restrict__ Bt,
        const float* __restrict__ stem,
        const float* __restrict__ wC,
        float* __restrict__ out) {
    // 2048 blocks: xcd = bid&7; per XCD: 64 n-panels x 4 m-tiles, m fastest (panel L2 reuse).
    const int bid = blockIdx.x;
    const int xcd = bid & 7, s = bid >> 3;          // s: 0..255
    const int m0 = (s & 3) << 8;                    // 4 m-tiles of 256 rows
    const int n0 = ((xcd << 6) + (s >> 2)) << 7;    // 512 n-panels of 128 cols
    const int t = threadIdx.x;                      // 0..511
    const int lane = t & 63, wid = t >> 6;          // 8 waves: wr 0..3 (64 rows), wcn 0..1 (64 cols)
    const int wr = wid >> 1, wcn = wid & 1;
    const int q = lane >> 4, rl = lane & 15;
    const int soff = ((q ^ ((rl >> 2) & 3)) << 4);  // XOR-swizzle byte offset (matches writers)

    __shared__ __align__(16) unsigned short ldsb[36864];  // 72KB: 3 bufs x (A 16KB + B 8KB)

    f32x4 acc[4][4];
    const f32x4 z = {0.f, 0.f, 0.f, 0.f};
    #pragma unroll
    for (int i = 0; i < 4; ++i)
        #pragma unroll
        for (int j = 0; j < 4; ++j) acc[i][j] = z;

    // per-thread staging sources (pre-swizzled in ws -> linear LDS dest is correct)
    const unsigned short* a_src = attn_sw + (size_t)(m0 + (t >> 2)) * 512 + (t & 3) * 8;
    const unsigned short* b_src = Bt + (size_t)(n0 + (t >> 2)) * 512 + (t & 3) * 8;

// 3 global_load_lds per thread (2 A + 1 B); buf ring = kt % 3
#define STAGE(kt) do { \
    unsigned short* dst_ = ldsb + ((kt) % 3) * 12288; \
    const int ko_ = (kt) * 32; \
    gload_lds16(a_src + ko_, dst_ + t * 8); \
    gload_lds16(a_src + 65536 + ko_, dst_ + 4096 + t * 8); \
    gload_lds16(b_src + ko_, dst_ + 8192 + t * 8); \
} while (0)

// One K-step, ONE barrier. Order: wait stage(kt) landed -> barrier (all waves done
// reading buf((kt+2)%3) in compute(kt-1)) -> issue STAGE(kt+2) -> compute(kt).
#define KSTEP(kt, STG, VMSTR) do { \
    asm volatile("s_waitcnt vmcnt(" VMSTR ")" ::: "memory"); \
    __builtin_amdgcn_s_barrier(); \
    __builtin_amdgcn_sched_barrier(0); \
    if (STG) STAGE((kt) + 2); \
    const char* abase_ = (const char*)(ldsb + ((kt) % 3) * 12288); \
    const char* bbase_ = abase_ + 16384; \
    bf16x8 af_[4], bfv_[4]; \
    _Pragma("unroll") \
    for (int f_ = 0; f_ < 4; ++f_) \
        af_[f_] = *(const bf16x8*)(abase_ + (wr * 64 + f_ * 16 + rl) * 64 + soff); \
    _Pragma("unroll") \
    for (int j_ = 0; j_ < 4; ++j_) \
        bfv_[j_] = *(const bf16x8*)(bbase_ + (wcn * 64 + j_ * 16 + rl) * 64 + soff); \
    __builtin_amdgcn_s_setprio(1); \
    _Pragma("unroll") \
    for (int fm_ = 0; fm_ < 4; ++fm_) \
        _Pragma("unroll") \
        for (int j_ = 0; j_ < 4; ++j_) \
            acc[fm_][j_] = __builtin_amdgcn_mfma_f32_16x16x32_bf16( \
                af_[fm_], bfv_[j_], acc[fm_][j_], 0, 0, 0); \
    __builtin_amdgcn_s_setprio(0); \
    __builtin_amdgcn_sched_barrier(0); \
} while (0)

    STAGE(0); STAGE(1);
    KSTEP(0, 1, "3");  KSTEP(1, 1, "3");  KSTEP(2, 1, "3");  KSTEP(3, 1, "3");
    KSTEP(4, 1, "3");  KSTEP(5, 1, "3");  KSTEP(6, 1, "3");  KSTEP(7, 1, "3");
    KSTEP(8, 1, "3");  KSTEP(9, 1, "3");  KSTEP(10, 1, "3"); KSTEP(11, 1, "3");
    KSTEP(12, 1, "3"); KSTEP(13, 1, "3"); KSTEP(14, 0, "3"); KSTEP(15, 0, "0");
#undef STAGE
#undef KSTEP
    __syncthreads();  // full fence before LDS reuse by epilogue

    // ---- epilogue: 4 passes of 64 rows; acc -> LDS [64][132] -> full-row (512B x2) f32x4 RMW ----
    float* cs = (float*)ldsb;
    #pragma unroll
    for (int sb = 0; sb < 4; ++sb) {
        if (sb) __syncthreads();
        if (wr == sb) {
            #pragma unroll
            for (int fm = 0; fm < 4; ++fm) {
                #pragma unroll
                for (int n = 0; n < 4; ++n) {
                    int c = wcn * 64 + n * 16 + rl;
                    #pragma unroll
                    for (int i = 0; i < 4; ++i)
                        cs[(fm * 16 + q * 4 + i) * 132 + c] = acc[fm][n][i];
                }
            }
        }
        __syncthreads();
        #pragma unroll
        for (int i2 = 0; i2 < 4; ++i2) {
            int row = i2 * 16 + (t >> 5);          // 0..63 within pass
            int col = (t & 31) * 4;                // 32 lanes x 16B = full 512B row
            int b = m0 + sb * 64 + row;
            size_t gb = (size_t)b * 65536 + (size_t)n0 + col;
            f32x4 cv = *(const f32x4*)&cs[row * 132 + col];
            f32x4 sv = *(const f32x4*)&stem[gb];
            f32x4 wv = *(const f32x4*)&wC[((size_t)b << 8) + (n0 & 255) + col];
            f32x4 ov;
            #pragma unroll
            for (int jj = 0; jj < 4; ++jj)
                ov[jj] = sv[jj] + (cv[jj] - sv[jj]) * wv[jj];
            *(f32x4*)&out[gb] = ov;
        }
    }
}

// ---------- Kernel C (fallback, ws too small): in-kernel convert+transpose, 128^2 ----------
__global__ void gemm_fb(const unsigned short* __restrict__ attn_sw,
                        const float* __restrict__ vocab,
                        const float* __restrict__ stem,
                        const float* __restrict__ wC,
                        float* __restrict__ out) {
    const int tile_m = blockIdx.x & 7;
    const int tile_n = blockIdx.x >> 3;
    const int m0 = tile_m << 7;
    const int n0 = tile_n << 7;
    const int t = threadIdx.x;
    const int lane = t & 63;
    const int wv = t >> 6;
    const int wm = wv >> 1, wn = wv & 1;

    __shared__ unsigned short Asl[128 * 32];
    __shared__ unsigned short Bsl[128 * 32];

    f32x4 acc[4][4];
    const f32x4 z = {0.f, 0.f, 0.f, 0.f};
    #pragma unroll
    for (int i = 0; i < 4; ++i)
        #pragma unroll
        for (int j = 0; j < 4; ++j) acc[i][j] = z;

    const unsigned short* a_base = attn_sw + ((size_t)m0 << 9);
    const int q = lane >> 4;
    const int rl = lane & 15;

    for (int ks = 0; ks < 16; ++ks) {
        #pragma unroll
        for (int it = 0; it < 2; ++it) {
            int idx = it * 256 + t;
            int r = idx >> 2, blk = idx & 3;
            gload_lds16(a_base + r * 512 + ks * 32 + blk * 8, Asl + idx * 8);
        }
        #pragma unroll
        for (int it = 0; it < 2; ++it) {
            int lin = it * 256 + t;
            int pair = lin >> 5;
            int chunk = lin & 31;
            int k = pair * 2;
            const float* g0 = vocab + (size_t)(ks * 32 + k) * 65536 + n0 + chunk * 4;
            float4 v0 = *(const float4*)g0;
            float4 v1 = *(const float4*)(g0 + 65536);
            #pragma unroll
            for (int j = 0; j < 4; ++j) {
                int n = chunk * 4 + j;
                unsigned d = (unsigned)f2bf((&v0.x)[j]) | ((unsigned)f2bf((&v1.x)[j]) << 16);
                int ae = n * 32 + ((((k >> 3) ^ ((n >> 2) & 3))) << 3) + (k & 7);
                *(unsigned*)((char*)Bsl + ae * 2) = d;
            }
        }
        __syncthreads();
        bf16x8 af[4], bfr[4];
        #pragma unroll
        for (int f = 0; f < 4; ++f) {
            int r = wm * 64 + f * 16 + rl;
            af[f] = *(const bf16x8*)((const char*)Asl + r * 64 + ((q ^ ((r >> 2) & 3)) << 4));
            int c = wn * 64 + f * 16 + rl;
            bfr[f] = *(const bf16x8*)((const char*)Bsl + c * 64 + ((q ^ ((c >> 2) & 3)) << 4));
        }
        __syncthreads();
        #pragma unroll
        for (int fm = 0; fm < 4; ++fm)
            #pragma unroll
            for (int fn = 0; fn < 4; ++fn)
                acc[fm][fn] = __builtin_amdgcn_mfma_f32_16x16x32_bf16(af[fm], bfr[fn], acc[fm][fn], 0, 0, 0);
    }

    #pragma unroll
    for (int fm = 0; fm < 4; ++fm) {
        int rbase = m0 + wm * 64 + fm * 16 + ((lane >> 4) << 2);
        #pragma unroll
        for (int fn = 0; fn < 4; ++fn) {
            int c = n0 + wn * 64 + fn * 16 + (lane & 15);
            #pragma unroll
            for (int i = 0; i < 4; ++i) {
                int b = rbase + i;
                float w = wC[(b << 8) + (c & 255)];
                size_t o = ((size_t)b << 16) + (size_t)c;
                float sv = stem[o];
                out[o] = sv + (acc[fm][fn][i] - sv) * w;
            }
        }
    }
}

// Fallback producers (only used when ws too small for Bt)
__global__ void attn_kernel(const float* __restrict__ morphosyn,
                            const float* __restrict__ W,
                            unsigned short* __restrict__ attn_sw) {
    const int b = blockIdx.x;
    const int t = threadIdx.x;
    __shared__ float ms[128];
    __shared__ float red[4];
    if (t < 128) ms[t] = morphosyn[b * 128 + t];
    __syncthreads();
    float acc0 = 0.f, acc1 = 0.f;
    #pragma unroll 8
    for (int dm = 0; dm < 128; ++dm) {
        float m = ms[dm];
        acc0 = fmaf(m, W[dm * 512 + t], acc0);
        acc1 = fmaf(m, W[dm * 512 + t + 256], acc1);
    }
    const int lane = t & 63, wid = t >> 6;
    float mx = fmaxf(acc0, acc1);
    #pragma unroll
    for (int o = 32; o; o >>= 1) mx = fmaxf(mx, __shfl_xor(mx, o));
    if (lane == 0) red[wid] = mx;
    __syncthreads();
    mx = fmaxf(fmaxf(red[0], red[1]), fmaxf(red[2], red[3]));
    __syncthreads();
    float e0 = __expf(acc0 - mx), e1 = __expf(acc1 - mx);
    float sm = e0 + e1;
    #pragma unroll
    for (int o = 32; o; o >>= 1) sm += __shfl_xor(sm, o);
    if (lane == 0) red[wid] = sm;
    __syncthreads();
    sm = red[0] + red[1] + red[2] + red[3];
    const float inv = 1.0f / sm;
    const int swz = (b >> 2) & 3;
    #pragma unroll
    for (int h = 0; h < 2; ++h) {
        int v = t + h * 256;
        int ae = (v >> 5) * 32 + ((((v >> 3) & 3) ^ swz) << 3) + (v & 7);
        attn_sw[b * 512 + ae] = f2bf((h ? e1 : e0) * inv);
    }
}

__global__ void wc_kernel(const float* __restrict__ logits,
                          const float* __restrict__ alpha,
                          const float* __restrict__ beta,
                          const float* __restrict__ phi,
                          float* __restrict__ wC) {
    const int b = blockIdx.x;
    const int t = threadIdx.x;
    const int lane = t & 63, wid = t >> 6;
    __shared__ float part[4][256];
    __shared__ float wsum[4];
    float a0 = alpha[0], a1 = alpha[1];
    float am = fmaxf(a0, a1);
    float ea0 = __expf(a0 - am), ea1 = __expf(a1 - am);
    float as = ea0 + ea1;
    float b0 = beta[0], b1 = beta[1];
    float bm = fmaxf(b0, b1);
    float eb0 = __expf(b0 - bm), eb1 = __expf(b1 - bm);
    float bs = eb0 + eb1;
    float p[5];
    float pm = -1e30f;
    #pragma unroll
    for (int k = 0; k < 5; ++k) { p[k] = phi[k]; pm = fmaxf(pm, p[k]); }
    float ps = 0.f;
    #pragma unroll
    for (int k = 0; k < 5; ++k) { p[k] = __expf(p[k] - pm); ps += p[k]; }
    const float wa[2] = {ea0 / as, ea1 / as}, wb[2] = {eb0 / bs, eb1 / bs};
    f32x4 accv = {0.f, 0.f, 0.f, 0.f};
    #pragma unroll
    for (int s5 = 0; s5 < 5; ++s5) {
        int sl = wid * 5 + s5;
        int i = sl >= 10;
        int j = (sl / 5) & 1;
        int k = sl - (sl / 5) * 5;
        const float* base = logits + ((size_t)(((i * 2 + j) * 1024 + b) * 5 + k)) * 256;
        f32x4 x = *(const f32x4*)(base + lane * 4);
        float mx = fmaxf(fmaxf(x[0], x[1]), fmaxf(x[2], x[3]));
        #pragma unroll
        for (int o = 32; o; o >>= 1) mx = fmaxf(mx, __shfl_xor(mx, o));
        f32x4 e;
        float sm = 0.f;
        #pragma unroll
        for (int r = 0; r < 4; ++r) { e[r] = __expf(x[r] - mx); sm += e[r]; }
        #pragma unroll
        for (int o = 32; o; o >>= 1) sm += __shfl_xor(sm, o);
        float w = wa[i] * wb[j] * (p[k] / ps) / sm;
        #pragma unroll
        for (int r = 0; r < 4; ++r) accv[r] += w * e[r];
    }
    *(f32x4*)&part[wid][lane * 4] = accv;
    __syncthreads();
    float v = part[0][t] + part[1][t] + part[2][t] + part[3][t];
    #pragma unroll
    for (int o = 1; o < 64; o <<= 1) {
        float u = __shfl_up(v, o);
        if (lane >= o) v += u;
    }
    if (lane == 63) wsum[wid] = v;
    __syncthreads();
    float offv = 0.f;
    for (int w2 = 0; w2 < wid; ++w2) offv += wsum[w2];
    wC[b * 256 + t] = v + offv;
}

extern "C" void kernel_launch(void* const* d_in, const int* in_sizes, int n_in,
                              void* d_out, int out_size, void* d_ws, size_t ws_size,
                              hipStream_t stream) {
    const float* stem    = (const float*)d_in[0];
    const float* morpho  = (const float*)d_in[1];
    const float* logits  = (const float*)d_in[2];
    const float* W       = (const float*)d_in[3];
    const float* vocab   = (const float*)d_in[4];
    const float* alpha   = (const float*)d_in[5];
    const float* beta    = (const float*)d_in[6];
    const float* phi     = (const float*)d_in[7];
    float* out = (float*)d_out;

    unsigned short* attn_sw = (unsigned short*)d_ws;                 // 1 MB
    float* wC = (float*)((char*)d_ws + (1 << 20));                   // 1 MB
    unsigned short* Bt = (unsigned short*)((char*)d_ws + (2 << 20)); // 64 MB

    const size_t need = (size_t)(2 << 20) + (size_t)64 * 1024 * 1024;

    if (ws_size >= need) {
        prepass_kernel<<<6144, 256, 0, stream>>>(vocab, Bt, logits, alpha, beta, phi, wC,
                                                 morpho, W, attn_sw);
        gemm_kernel<<<2048, 512, 0, stream>>>(attn_sw, Bt, stem, wC, out);
    } else {
        attn_kernel<<<1024, 256, 0, stream>>>(morpho, W, attn_sw);
        wc_kernel<<<1024, 256, 0, stream>>>(logits, alpha, beta, phi, wC);
        gemm_fb<<<4096, 256, 0, stream>>>(attn_sw, vocab, stem, wC, out);
    }
}

// Round 14
// 228.907 us; speedup vs baseline: 1.1625x; 1.0490x over previous
//
#include <hip/hip_runtime.h>
#include <hip/hip_bf16.h>
#include <stdint.h>

typedef __bf16 bf16x8 __attribute__((ext_vector_type(8)));
typedef float f32x4 __attribute__((ext_vector_type(4)));

static __device__ __forceinline__ unsigned short f2bf(float x) {
    union { float f; unsigned u; } v; v.f = x;
    unsigned r = v.u + 0x7FFFu + ((v.u >> 16) & 1u);  // round-to-nearest-even
    return (unsigned short)(r >> 16);
}

static __device__ __forceinline__ void gload_lds16(const void* g, void* l) {
    auto gp = (const unsigned int __attribute__((address_space(1)))*)(reinterpret_cast<uintptr_t>(g));
    auto lp = (unsigned int __attribute__((address_space(3)))*)(reinterpret_cast<uintptr_t>(l));
    __builtin_amdgcn_global_load_lds(gp, lp, 16, 0, 0);
}

// ---------- Fused pre-pass: conv (blocks 0..4095) | wc (4096..5119) | attn (5120..6143) ----------
__global__ __launch_bounds__(256, 4) void prepass_kernel(
        const float* __restrict__ vocab, unsigned short* __restrict__ Bt,
        const float* __restrict__ logits, const float* __restrict__ alpha,
        const float* __restrict__ beta, const float* __restrict__ phi,
        float* __restrict__ wC,
        const float* __restrict__ morphosyn, const float* __restrict__ W,
        unsigned short* __restrict__ attn_sw) {
    const int bid = blockIdx.x;
    const int t = threadIdx.x;
    const int lane = t & 63, wid = t >> 6;

    if (bid < 4096) {
        // ---- conv: vocab f32 [v][n'] -> bf16 Bt[n'][v], 16B-block XOR-swizzled per row ----
        const int n0 = bid * 16;
        __shared__ unsigned int T[16 * 256];  // [n][v/2] dwords
        #pragma unroll
        for (int it = 0; it < 4; ++it) {
            int p = it * 256 + t;
            int v = (p >> 2) * 2;
            int col4 = p & 3;
            const float* g0 = vocab + (size_t)v * 65536 + n0 + col4 * 4;
            float4 a = *(const float4*)g0;
            float4 c = *(const float4*)(g0 + 65536);
            #pragma unroll
            for (int j = 0; j < 4; ++j) {
                int n = col4 * 4 + j;
                unsigned d = (unsigned)f2bf((&a.x)[j]) | ((unsigned)f2bf((&c.x)[j]) << 16);
                T[n * 256 + (v >> 1)] = d;
            }
        }
        __syncthreads();
        #pragma unroll
        for (int it = 0; it < 4; ++it) {
            int qq = it * 256 + t;
            int r = qq >> 6, c = qq & 63;
            int swz = ((n0 + r) >> 2) & 3;
            int dc = (c & ~3) | ((c & 3) ^ swz);
            uint4 d = *(const uint4*)(&T[r * 256 + c * 4]);
            *(uint4*)(Bt + (size_t)(n0 + r) * 512 + dc * 8) = d;
        }
    } else if (bid < 5120) {
        // ---- wc ----
        const int b = bid - 4096;
        __shared__ float part[4][256];
        __shared__ float wsum[4];

        float a0 = alpha[0], a1 = alpha[1];
        float am = fmaxf(a0, a1);
        float ea0 = __expf(a0 - am), ea1 = __expf(a1 - am);
        float as = ea0 + ea1;
        float b0 = beta[0], b1 = beta[1];
        float bm = fmaxf(b0, b1);
        float eb0 = __expf(b0 - bm), eb1 = __expf(b1 - bm);
        float bs = eb0 + eb1;
        float p[5];
        float pm = -1e30f;
        #pragma unroll
        for (int k = 0; k < 5; ++k) { p[k] = phi[k]; pm = fmaxf(pm, p[k]); }
        float ps = 0.f;
        #pragma unroll
        for (int k = 0; k < 5; ++k) { p[k] = __expf(p[k] - pm); ps += p[k]; }
        const float wa[2] = {ea0 / as, ea1 / as}, wb[2] = {eb0 / bs, eb1 / bs};

        f32x4 accv = {0.f, 0.f, 0.f, 0.f};
        #pragma unroll
        for (int s5 = 0; s5 < 5; ++s5) {
            int sl = wid * 5 + s5;
            int i = sl >= 10;
            int j = (sl / 5) & 1;
            int k = sl - (sl / 5) * 5;
            const float* base = logits + ((size_t)(((i * 2 + j) * 1024 + b) * 5 + k)) * 256;
            f32x4 x = *(const f32x4*)(base + lane * 4);
            float mx = fmaxf(fmaxf(x[0], x[1]), fmaxf(x[2], x[3]));
            #pragma unroll
            for (int o = 32; o; o >>= 1) mx = fmaxf(mx, __shfl_xor(mx, o));
            f32x4 e;
            float sm = 0.f;
            #pragma unroll
            for (int r = 0; r < 4; ++r) { e[r] = __expf(x[r] - mx); sm += e[r]; }
            #pragma unroll
            for (int o = 32; o; o >>= 1) sm += __shfl_xor(sm, o);
            float w = wa[i] * wb[j] * (p[k] / ps) / sm;
            #pragma unroll
            for (int r = 0; r < 4; ++r) accv[r] += w * e[r];
        }
        *(f32x4*)&part[wid][lane * 4] = accv;
        __syncthreads();
        float v = part[0][t] + part[1][t] + part[2][t] + part[3][t];
        #pragma unroll
        for (int o = 1; o < 64; o <<= 1) {
            float u = __shfl_up(v, o);
            if (lane >= o) v += u;
        }
        if (lane == 63) wsum[wid] = v;
        __syncthreads();
        float offv = 0.f;
        for (int w2 = 0; w2 < wid; ++w2) offv += wsum[w2];
        wC[b * 256 + t] = v + offv;
    } else {
        // ---- attn ----
        const int b = bid - 5120;
        __shared__ float ms[128];
        __shared__ float red[4];
        if (t < 128) ms[t] = morphosyn[b * 128 + t];
        __syncthreads();
        float acc0 = 0.f, acc1 = 0.f;
        #pragma unroll 8
        for (int dm = 0; dm < 128; ++dm) {
            float m = ms[dm];
            acc0 = fmaf(m, W[dm * 512 + t], acc0);
            acc1 = fmaf(m, W[dm * 512 + t + 256], acc1);
        }
        float mx = fmaxf(acc0, acc1);
        #pragma unroll
        for (int o = 32; o; o >>= 1) mx = fmaxf(mx, __shfl_xor(mx, o));
        if (lane == 0) red[wid] = mx;
        __syncthreads();
        mx = fmaxf(fmaxf(red[0], red[1]), fmaxf(red[2], red[3]));
        __syncthreads();
        float e0 = __expf(acc0 - mx), e1 = __expf(acc1 - mx);
        float sm = e0 + e1;
        #pragma unroll
        for (int o = 32; o; o >>= 1) sm += __shfl_xor(sm, o);
        if (lane == 0) red[wid] = sm;
        __syncthreads();
        sm = red[0] + red[1] + red[2] + red[3];
        const float inv = 1.0f / sm;
        const int swz = (b >> 2) & 3;
        #pragma unroll
        for (int h = 0; h < 2; ++h) {
            int v = t + h * 256;
            int ae = (v >> 5) * 32 + ((((v >> 3) & 3) ^ swz) << 3) + (v & 7);
            attn_sw[b * 512 + ae] = f2bf((h ? e1 : e0) * inv);
        }
    }
}

// ---------- Kernel C (fast): 256x128 tile, BK=32, 8 waves (4x2), 3-buf ring ----------
// R11 K-loop + early-stem epilogue (T14). launch_bounds(512,4): 64-VGPR cap keeps wave total
// at 64+64(AGPR)=128 -> 4 waves/SIMD -> 2 blocks/CU. Only stem (HBM) is hoisted (16 regs);
// wC is L2-resident and loads inline. R12's 32-reg hoist hit 132 total -> 1 block/CU cliff.
__global__ __launch_bounds__(512, 4) void gemm_kernel(
        const unsigned short* __restrict__ attn_sw,
        const unsigned short* __restrict__ Bt,
        const float* __restrict__ stem,
        const float* __restrict__ wC,
        float* __restrict__ out) {
    // 2048 blocks: xcd = bid&7; per XCD: 64 n-panels x 4 m-tiles, m fastest (panel L2 reuse).
    const int bid = blockIdx.x;
    const int xcd = bid & 7, s = bid >> 3;          // s: 0..255
    const int m0 = (s & 3) << 8;                    // 4 m-tiles of 256 rows
    const int n0 = ((xcd << 6) + (s >> 2)) << 7;    // 512 n-panels of 128 cols
    const int t = threadIdx.x;                      // 0..511
    const int lane = t & 63, wid = t >> 6;          // 8 waves: wr 0..3 (64 rows), wcn 0..1 (64 cols)
    const int wr = wid >> 1, wcn = wid & 1;
    const int q = lane >> 4, rl = lane & 15;
    const int soff = ((q ^ ((rl >> 2) & 3)) << 4);  // XOR-swizzle byte offset (matches writers)

    __shared__ __align__(16) unsigned short ldsb[36864];  // 72KB: 3 bufs x (A 16KB + B 8KB)

    f32x4 acc[4][4];
    const f32x4 z = {0.f, 0.f, 0.f, 0.f};
    #pragma unroll
    for (int i = 0; i < 4; ++i)
        #pragma unroll
        for (int j = 0; j < 4; ++j) acc[i][j] = z;

    // per-thread staging sources (pre-swizzled in ws -> linear LDS dest is correct)
    const unsigned short* a_src = attn_sw + (size_t)(m0 + (t >> 2)) * 512 + (t & 3) * 8;
    const unsigned short* b_src = Bt + (size_t)(n0 + (t >> 2)) * 512 + (t & 3) * 8;

// 3 global_load_lds per thread (2 A + 1 B); buf ring = kt % 3
#define STAGE(kt) do { \
    unsigned short* dst_ = ldsb + ((kt) % 3) * 12288; \
    const int ko_ = (kt) * 32; \
    gload_lds16(a_src + ko_, dst_ + t * 8); \
    gload_lds16(a_src + 65536 + ko_, dst_ + 4096 + t * 8); \
    gload_lds16(b_src + ko_, dst_ + 8192 + t * 8); \
} while (0)

// One K-step, ONE barrier. Order: wait stage(kt) landed -> barrier (all waves done
// reading buf((kt+2)%3) in compute(kt-1)) -> issue STAGE(kt+2) -> compute(kt).
#define KSTEP(kt, STG, VMSTR) do { \
    asm volatile("s_waitcnt vmcnt(" VMSTR ")" ::: "memory"); \
    __builtin_amdgcn_s_barrier(); \
    __builtin_amdgcn_sched_barrier(0); \
    if (STG) STAGE((kt) + 2); \
    const char* abase_ = (const char*)(ldsb + ((kt) % 3) * 12288); \
    const char* bbase_ = abase_ + 16384; \
    bf16x8 af_[4], bfv_[4]; \
    _Pragma("unroll") \
    for (int f_ = 0; f_ < 4; ++f_) \
        af_[f_] = *(const bf16x8*)(abase_ + (wr * 64 + f_ * 16 + rl) * 64 + soff); \
    _Pragma("unroll") \
    for (int j_ = 0; j_ < 4; ++j_) \
        bfv_[j_] = *(const bf16x8*)(bbase_ + (wcn * 64 + j_ * 16 + rl) * 64 + soff); \
    __builtin_amdgcn_s_setprio(1); \
    _Pragma("unroll") \
    for (int fm_ = 0; fm_ < 4; ++fm_) \
        _Pragma("unroll") \
        for (int j_ = 0; j_ < 4; ++j_) \
            acc[fm_][j_] = __builtin_amdgcn_mfma_f32_16x16x32_bf16( \
                af_[fm_], bfv_[j_], acc[fm_][j_], 0, 0, 0); \
    __builtin_amdgcn_s_setprio(0); \
    __builtin_amdgcn_sched_barrier(0); \
} while (0)

    STAGE(0); STAGE(1);
    KSTEP(0, 1, "3");  KSTEP(1, 1, "3");  KSTEP(2, 1, "3");  KSTEP(3, 1, "3");
    KSTEP(4, 1, "3");  KSTEP(5, 1, "3");  KSTEP(6, 1, "3");  KSTEP(7, 1, "3");
    KSTEP(8, 1, "3");  KSTEP(9, 1, "3");  KSTEP(10, 1, "3"); KSTEP(11, 1, "3");
    KSTEP(12, 1, "3"); KSTEP(13, 1, "3"); KSTEP(14, 0, "3"); KSTEP(15, 0, "0");
#undef STAGE
#undef KSTEP

    // ---- epilogue: 4 passes of 64 rows; stem loads issued EARLY (before the cs bounce),
    // wC (L2-resident) inline; then full-row (512B x2... one 512B row) f32x4 RMW. ----
    float* cs = (float*)ldsb;
    const int erow = t >> 5;                       // 0..15
    const int ecol = (t & 31) * 4;                 // 32 lanes x 16B = full 512B row
    #pragma unroll
    for (int sb = 0; sb < 4; ++sb) {
        // early-issue stem loads for this pass; HBM latency hides under the LDS bounce
        f32x4 sv[4];
        #pragma unroll
        for (int i2 = 0; i2 < 4; ++i2) {
            int b = m0 + sb * 64 + i2 * 16 + erow;
            sv[i2] = *(const f32x4*)&stem[(size_t)b * 65536 + (size_t)n0 + ecol];
        }
        __syncthreads();   // K-loop LDS done (sb=0) / previous pass cs reads done (sb>0)
        if (wr == sb) {
            #pragma unroll
            for (int fm = 0; fm < 4; ++fm) {
                #pragma unroll
                for (int n = 0; n < 4; ++n) {
                    int c = wcn * 64 + n * 16 + rl;
                    #pragma unroll
                    for (int i = 0; i < 4; ++i)
                        cs[(fm * 16 + q * 4 + i) * 132 + c] = acc[fm][n][i];
                }
            }
        }
        __syncthreads();
        #pragma unroll
        for (int i2 = 0; i2 < 4; ++i2) {
            int row = i2 * 16 + erow;
            int b = m0 + sb * 64 + row;
            size_t gb = (size_t)b * 65536 + (size_t)n0 + ecol;
            f32x4 cv = *(const f32x4*)&cs[row * 132 + ecol];
            f32x4 wv = *(const f32x4*)&wC[((size_t)b << 8) + (n0 & 255) + ecol];
            f32x4 ov;
            #pragma unroll
            for (int jj = 0; jj < 4; ++jj)
                ov[jj] = sv[i2][jj] + (cv[jj] - sv[i2][jj]) * wv[jj];
            *(f32x4*)&out[gb] = ov;
        }
    }
}

// ---------- Kernel C (fallback, ws too small): in-kernel convert+transpose, 128^2 ----------
__global__ void gemm_fb(const unsigned short* __restrict__ attn_sw,
                        const float* __restrict__ vocab,
                        const float* __restrict__ stem,
                        const float* __restrict__ wC,
                        float* __restrict__ out) {
    const int tile_m = blockIdx.x & 7;
    const int tile_n = blockIdx.x >> 3;
    const int m0 = tile_m << 7;
    const int n0 = tile_n << 7;
    const int t = threadIdx.x;
    const int lane = t & 63;
    const int wv = t >> 6;
    const int wm = wv >> 1, wn = wv & 1;

    __shared__ unsigned short Asl[128 * 32];
    __shared__ unsigned short Bsl[128 * 32];

    f32x4 acc[4][4];
    const f32x4 z = {0.f, 0.f, 0.f, 0.f};
    #pragma unroll
    for (int i = 0; i < 4; ++i)
        #pragma unroll
        for (int j = 0; j < 4; ++j) acc[i][j] = z;

    const unsigned short* a_base = attn_sw + ((size_t)m0 << 9);
    const int q = lane >> 4;
    const int rl = lane & 15;

    for (int ks = 0; ks < 16; ++ks) {
        #pragma unroll
        for (int it = 0; it < 2; ++it) {
            int idx = it * 256 + t;
            int r = idx >> 2, blk = idx & 3;
            gload_lds16(a_base + r * 512 + ks * 32 + blk * 8, Asl + idx * 8);
        }
        #pragma unroll
        for (int it = 0; it < 2; ++it) {
            int lin = it * 256 + t;
            int pair = lin >> 5;
            int chunk = lin & 31;
            int k = pair * 2;
            const float* g0 = vocab + (size_t)(ks * 32 + k) * 65536 + n0 + chunk * 4;
            float4 v0 = *(const float4*)g0;
            float4 v1 = *(const float4*)(g0 + 65536);
            #pragma unroll
            for (int j = 0; j < 4; ++j) {
                int n = chunk * 4 + j;
                unsigned d = (unsigned)f2bf((&v0.x)[j]) | ((unsigned)f2bf((&v1.x)[j]) << 16);
                int ae = n * 32 + ((((k >> 3) ^ ((n >> 2) & 3))) << 3) + (k & 7);
                *(unsigned*)((char*)Bsl + ae * 2) = d;
            }
        }
        __syncthreads();
        bf16x8 af[4], bfr[4];
        #pragma unroll
        for (int f = 0; f < 4; ++f) {
            int r = wm * 64 + f * 16 + rl;
            af[f] = *(const bf16x8*)((const char*)Asl + r * 64 + ((q ^ ((r >> 2) & 3)) << 4));
            int c = wn * 64 + f * 16 + rl;
            bfr[f] = *(const bf16x8*)((const char*)Bsl + c * 64 + ((q ^ ((c >> 2) & 3)) << 4));
        }
        __syncthreads();
        #pragma unroll
        for (int fm = 0; fm < 4; ++fm)
            #pragma unroll
            for (int fn = 0; fn < 4; ++fn)
                acc[fm][fn] = __builtin_amdgcn_mfma_f32_16x16x32_bf16(af[fm], bfr[fn], acc[fm][fn], 0, 0, 0);
    }

    #pragma unroll
    for (int fm = 0; fm < 4; ++fm) {
        int rbase = m0 + wm * 64 + fm * 16 + ((lane >> 4) << 2);
        #pragma unroll
        for (int fn = 0; fn < 4; ++fn) {
            int c = n0 + wn * 64 + fn * 16 + (lane & 15);
            #pragma unroll
            for (int i = 0; i < 4; ++i) {
                int b = rbase + i;
                float w = wC[(b << 8) + (c & 255)];
                size_t o = ((size_t)b << 16) + (size_t)c;
                float sv = stem[o];
                out[o] = sv + (acc[fm][fn][i] - sv) * w;
            }
        }
    }
}

// Fallback producers (only used when ws too small for Bt)
__global__ void attn_kernel(const float* __restrict__ morphosyn,
                            const float* __restrict__ W,
                            unsigned short* __restrict__ attn_sw) {
    const int b = blockIdx.x;
    const int t = threadIdx.x;
    __shared__ float ms[128];
    __shared__ float red[4];
    if (t < 128) ms[t] = morphosyn[b * 128 + t];
    __syncthreads();
    float acc0 = 0.f, acc1 = 0.f;
    #pragma unroll 8
    for (int dm = 0; dm < 128; ++dm) {
        float m = ms[dm];
        acc0 = fmaf(m, W[dm * 512 + t], acc0);
        acc1 = fmaf(m, W[dm * 512 + t + 256], acc1);
    }
    const int lane = t & 63, wid = t >> 6;
    float mx = fmaxf(acc0, acc1);
    #pragma unroll
    for (int o = 32; o; o >>= 1) mx = fmaxf(mx, __shfl_xor(mx, o));
    if (lane == 0) red[wid] = mx;
    __syncthreads();
    mx = fmaxf(fmaxf(red[0], red[1]), fmaxf(red[2], red[3]));
    __syncthreads();
    float e0 = __expf(acc0 - mx), e1 = __expf(acc1 - mx);
    float sm = e0 + e1;
    #pragma unroll
    for (int o = 32; o; o >>= 1) sm += __shfl_xor(sm, o);
    if (lane == 0) red[wid] = sm;
    __syncthreads();
    sm = red[0] + red[1] + red[2] + red[3];
    const float inv = 1.0f / sm;
    const int swz = (b >> 2) & 3;
    #pragma unroll
    for (int h = 0; h < 2; ++h) {
        int v = t + h * 256;
        int ae = (v >> 5) * 32 + ((((v >> 3) & 3) ^ swz) << 3) + (v & 7);
        attn_sw[b * 512 + ae] = f2bf((h ? e1 : e0) * inv);
    }
}

__global__ void wc_kernel(const float* __restrict__ logits,
                          const float* __restrict__ alpha,
                          const float* __restrict__ beta,
                          const float* __restrict__ phi,
                          float* __restrict__ wC) {
    const int b = blockIdx.x;
    const int t = threadIdx.x;
    const int lane = t & 63, wid = t >> 6;
    __shared__ float part[4][256];
    __shared__ float wsum[4];
    float a0 = alpha[0], a1 = alpha[1];
    float am = fmaxf(a0, a1);
    float ea0 = __expf(a0 - am), ea1 = __expf(a1 - am);
    float as = ea0 + ea1;
    float b0 = beta[0], b1 = beta[1];
    float bm = fmaxf(b0, b1);
    float eb0 = __expf(b0 - bm), eb1 = __expf(b1 - bm);
    float bs = eb0 + eb1;
    float p[5];
    float pm = -1e30f;
    #pragma unroll
    for (int k = 0; k < 5; ++k) { p[k] = phi[k]; pm = fmaxf(pm, p[k]); }
    float ps = 0.f;
    #pragma unroll
    for (int k = 0; k < 5; ++k) { p[k] = __expf(p[k] - pm); ps += p[k]; }
    const float wa[2] = {ea0 / as, ea1 / as}, wb[2] = {eb0 / bs, eb1 / bs};
    f32x4 accv = {0.f, 0.f, 0.f, 0.f};
    #pragma unroll
    for (int s5 = 0; s5 < 5; ++s5) {
        int sl = wid * 5 + s5;
        int i = sl >= 10;
        int j = (sl / 5) & 1;
        int k = sl - (sl / 5) * 5;
        const float* base = logits + ((size_t)(((i * 2 + j) * 1024 + b) * 5 + k)) * 256;
        f32x4 x = *(const f32x4*)(base + lane * 4);
        float mx = fmaxf(fmaxf(x[0], x[1]), fmaxf(x[2], x[3]));
        #pragma unroll
        for (int o = 32; o; o >>= 1) mx = fmaxf(mx, __shfl_xor(mx, o));
        f32x4 e;
        float sm = 0.f;
        #pragma unroll
        for (int r = 0; r < 4; ++r) { e[r] = __expf(x[r] - mx); sm += e[r]; }
        #pragma unroll
        for (int o = 32; o; o >>= 1) sm += __shfl_xor(sm, o);
        float w = wa[i] * wb[j] * (p[k] / ps) / sm;
        #pragma unroll
        for (int r = 0; r < 4; ++r) accv[r] += w * e[r];
    }
    *(f32x4*)&part[wid][lane * 4] = accv;
    __syncthreads();
    float v = part[0][t] + part[1][t] + part[2][t] + part[3][t];
    #pragma unroll
    for (int o = 1; o < 64; o <<= 1) {
        float u = __shfl_up(v, o);
        if (lane >= o) v += u;
    }
    if (lane == 63) wsum[wid] = v;
    __syncthreads();
    float offv = 0.f;
    for (int w2 = 0; w2 < wid; ++w2) offv += wsum[w2];
    wC[b * 256 + t] = v + offv;
}

extern "C" void kernel_launch(void* const* d_in, const int* in_sizes, int n_in,
                              void* d_out, int out_size, void* d_ws, size_t ws_size,
                              hipStream_t stream) {
    const float* stem    = (const float*)d_in[0];
    const float* morpho  = (const float*)d_in[1];
    const float* logits  = (const float*)d_in[2];
    const float* W       = (const float*)d_in[3];
    const float* vocab   = (const float*)d_in[4];
    const float* alpha   = (const float*)d_in[5];
    const float* beta    = (const float*)d_in[6];
    const float* phi     = (const float*)d_in[7];
    float* out = (float*)d_out;

    unsigned short* attn_sw = (unsigned short*)d_ws;                 // 1 MB
    float* wC = (float*)((char*)d_ws + (1 << 20));                   // 1 MB
    unsigned short* Bt = (unsigned short*)((char*)d_ws + (2 << 20)); // 64 MB

    const size_t need = (size_t)(2 << 20) + (size_t)64 * 1024 * 1024;

    if (ws_size >= need) {
        prepass_kernel<<<6144, 256, 0, stream>>>(vocab, Bt, logits, alpha, beta, phi, wC,
                                                 morpho, W, attn_sw);
        gemm_kernel<<<2048, 512, 0, stream>>>(attn_sw, Bt, stem, wC, out);
    } else {
        attn_kernel<<<1024, 256, 0, stream>>>(morpho, W, attn_sw);
        wc_kernel<<<1024, 256, 0, stream>>>(logits, alpha, beta, phi, wC);
        gemm_fb<<<4096, 256, 0, stream>>>(attn_sw, vocab, stem, wC, out);
    }
}

// Round 15
// 215.680 us; speedup vs baseline: 1.2338x; 1.0613x over previous
//
#include <hip/hip_runtime.h>
#include <hip/hip_bf16.h>
#include <stdint.h>

typedef __bf16 bf16x8 __attribute__((ext_vector_type(8)));
typedef float f32x4 __attribute__((ext_vector_type(4)));

static __device__ __forceinline__ unsigned short f2bf(float x) {
    union { float f; unsigned u; } v; v.f = x;
    unsigned r = v.u + 0x7FFFu + ((v.u >> 16) & 1u);  // round-to-nearest-even
    return (unsigned short)(r >> 16);
}

static __device__ __forceinline__ void gload_lds16(const void* g, void* l) {
    auto gp = (const unsigned int __attribute__((address_space(1)))*)(reinterpret_cast<uintptr_t>(g));
    auto lp = (unsigned int __attribute__((address_space(3)))*)(reinterpret_cast<uintptr_t>(l));
    __builtin_amdgcn_global_load_lds(gp, lp, 16, 0, 0);
}

// ---------- Fused pre-pass: conv32 (blocks 0..2047) | wc (2048..3071) | attn (3072..4095) ----------
// conv widened to 32-col tiles: each vocab row read as 128B contiguous (full line) vs 64B before.
__global__ __launch_bounds__(256, 4) void prepass_kernel(
        const float* __restrict__ vocab, unsigned short* __restrict__ Bt,
        const float* __restrict__ logits, const float* __restrict__ alpha,
        const float* __restrict__ beta, const float* __restrict__ phi,
        float* __restrict__ wC,
        const float* __restrict__ morphosyn, const float* __restrict__ W,
        unsigned short* __restrict__ attn_sw) {
    const int bid = blockIdx.x;
    const int t = threadIdx.x;
    const int lane = t & 63, wid = t >> 6;

    if (bid < 2048) {
        // ---- conv: vocab f32 [v][n'] -> bf16 Bt[n'][v], 16B-block XOR-swizzled per row ----
        const int n0 = bid * 32;
        __shared__ unsigned int T[32 * 256];  // [n][v/2] dwords, 32KB
        #pragma unroll
        for (int it = 0; it < 8; ++it) {
            int p = it * 256 + t;           // 0..2047
            int v = (p >> 3) * 2;           // even v, 0..510
            int col8 = p & 7;               // 8 x 16B = 128B per v-row
            const float* g0 = vocab + (size_t)v * 65536 + n0 + col8 * 4;
            float4 a = *(const float4*)g0;
            float4 c = *(const float4*)(g0 + 65536);
            #pragma unroll
            for (int j = 0; j < 4; ++j) {
                int n = col8 * 4 + j;
                unsigned d = (unsigned)f2bf((&a.x)[j]) | ((unsigned)f2bf((&c.x)[j]) << 16);
                T[n * 256 + (v >> 1)] = d;
            }
        }
        __syncthreads();
        #pragma unroll
        for (int it = 0; it < 8; ++it) {
            int qq = it * 256 + t;
            int r = qq >> 6, c = qq & 63;   // r: 0..31, c: 16B chunks
            int swz = ((n0 + r) >> 2) & 3;
            int dc = (c & ~3) | ((c & 3) ^ swz);
            uint4 d = *(const uint4*)(&T[r * 256 + c * 4]);
            *(uint4*)(Bt + (size_t)(n0 + r) * 512 + dc * 8) = d;
        }
    } else if (bid < 3072) {
        // ---- wc ----
        const int b = bid - 2048;
        __shared__ float part[4][256];
        __shared__ float wsum[4];

        float a0 = alpha[0], a1 = alpha[1];
        float am = fmaxf(a0, a1);
        float ea0 = __expf(a0 - am), ea1 = __expf(a1 - am);
        float as = ea0 + ea1;
        float b0 = beta[0], b1 = beta[1];
        float bm = fmaxf(b0, b1);
        float eb0 = __expf(b0 - bm), eb1 = __expf(b1 - bm);
        float bs = eb0 + eb1;
        float p[5];
        float pm = -1e30f;
        #pragma unroll
        for (int k = 0; k < 5; ++k) { p[k] = phi[k]; pm = fmaxf(pm, p[k]); }
        float ps = 0.f;
        #pragma unroll
        for (int k = 0; k < 5; ++k) { p[k] = __expf(p[k] - pm); ps += p[k]; }
        const float wa[2] = {ea0 / as, ea1 / as}, wb[2] = {eb0 / bs, eb1 / bs};

        f32x4 accv = {0.f, 0.f, 0.f, 0.f};
        #pragma unroll
        for (int s5 = 0; s5 < 5; ++s5) {
            int sl = wid * 5 + s5;
            int i = sl >= 10;
            int j = (sl / 5) & 1;
            int k = sl - (sl / 5) * 5;
            const float* base = logits + ((size_t)(((i * 2 + j) * 1024 + b) * 5 + k)) * 256;
            f32x4 x = *(const f32x4*)(base + lane * 4);
            float mx = fmaxf(fmaxf(x[0], x[1]), fmaxf(x[2], x[3]));
            #pragma unroll
            for (int o = 32; o; o >>= 1) mx = fmaxf(mx, __shfl_xor(mx, o));
            f32x4 e;
            float sm = 0.f;
            #pragma unroll
            for (int r = 0; r < 4; ++r) { e[r] = __expf(x[r] - mx); sm += e[r]; }
            #pragma unroll
            for (int o = 32; o; o >>= 1) sm += __shfl_xor(sm, o);
            float w = wa[i] * wb[j] * (p[k] / ps) / sm;
            #pragma unroll
            for (int r = 0; r < 4; ++r) accv[r] += w * e[r];
        }
        *(f32x4*)&part[wid][lane * 4] = accv;
        __syncthreads();
        float v = part[0][t] + part[1][t] + part[2][t] + part[3][t];
        #pragma unroll
        for (int o = 1; o < 64; o <<= 1) {
            float u = __shfl_up(v, o);
            if (lane >= o) v += u;
        }
        if (lane == 63) wsum[wid] = v;
        __syncthreads();
        float offv = 0.f;
        for (int w2 = 0; w2 < wid; ++w2) offv += wsum[w2];
        wC[b * 256 + t] = v + offv;
    } else {
        // ---- attn ----
        const int b = bid - 3072;
        __shared__ float ms[128];
        __shared__ float red[4];
        if (t < 128) ms[t] = morphosyn[b * 128 + t];
        __syncthreads();
        float acc0 = 0.f, acc1 = 0.f;
        #pragma unroll 8
        for (int dm = 0; dm < 128; ++dm) {
            float m = ms[dm];
            acc0 = fmaf(m, W[dm * 512 + t], acc0);
            acc1 = fmaf(m, W[dm * 512 + t + 256], acc1);
        }
        float mx = fmaxf(acc0, acc1);
        #pragma unroll
        for (int o = 32; o; o >>= 1) mx = fmaxf(mx, __shfl_xor(mx, o));
        if (lane == 0) red[wid] = mx;
        __syncthreads();
        mx = fmaxf(fmaxf(red[0], red[1]), fmaxf(red[2], red[3]));
        __syncthreads();
        float e0 = __expf(acc0 - mx), e1 = __expf(acc1 - mx);
        float sm = e0 + e1;
        #pragma unroll
        for (int o = 32; o; o >>= 1) sm += __shfl_xor(sm, o);
        if (lane == 0) red[wid] = sm;
        __syncthreads();
        sm = red[0] + red[1] + red[2] + red[3];
        const float inv = 1.0f / sm;
        const int swz = (b >> 2) & 3;
        #pragma unroll
        for (int h = 0; h < 2; ++h) {
            int v = t + h * 256;
            int ae = (v >> 5) * 32 + ((((v >> 3) & 3) ^ swz) << 3) + (v & 7);
            attn_sw[b * 512 + ae] = f2bf((h ? e1 : e0) * inv);
        }
    }
}

// ---------- Kernel C (fast): 256x128 tile, BK=32, 8 waves (4x2), split rings A:3 / B:4 ----------
// B (Bt, L3/HBM ~900cyc) gets depth-3 prefetch; A (attn_sw, L2 ~200cyc) depth-2.
// LDS = 3x16KB (A) + 4x8KB (B) = 80KB -> still 2 blocks/CU. Same post-barrier stage invariant
// as R11 (race-free, verified). Steady wait vmcnt(4) = {A(kt+1)x2, B(kt+1), B(kt+2)} in flight.
__global__ __launch_bounds__(512, 4) void gemm_kernel(
        const unsigned short* __restrict__ attn_sw,
        const unsigned short* __restrict__ Bt,
        const float* __restrict__ stem,
        const float* __restrict__ wC,
        float* __restrict__ out) {
    // 2048 blocks: xcd = bid&7; per XCD: 64 n-panels x 4 m-tiles, m fastest (panel L2 reuse).
    const int bid = blockIdx.x;
    const int xcd = bid & 7, s = bid >> 3;          // s: 0..255
    const int m0 = (s & 3) << 8;                    // 4 m-tiles of 256 rows
    const int n0 = ((xcd << 6) + (s >> 2)) << 7;    // 512 n-panels of 128 cols
    const int t = threadIdx.x;                      // 0..511
    const int lane = t & 63, wid = t >> 6;          // 8 waves: wr 0..3 (64 rows), wcn 0..1 (64 cols)
    const int wr = wid >> 1, wcn = wid & 1;
    const int q = lane >> 4, rl = lane & 15;
    const int soff = ((q ^ ((rl >> 2) & 3)) << 4);  // XOR-swizzle byte offset (matches writers)

    __shared__ __align__(16) unsigned short ldsb[40960];  // 80KB: A 3x8192el + B 4x4096el

    f32x4 acc[4][4];
    const f32x4 z = {0.f, 0.f, 0.f, 0.f};
    #pragma unroll
    for (int i = 0; i < 4; ++i)
        #pragma unroll
        for (int j = 0; j < 4; ++j) acc[i][j] = z;

    // per-thread staging sources (pre-swizzled in ws -> linear LDS dest is correct)
    const unsigned short* a_src = attn_sw + (size_t)(m0 + (t >> 2)) * 512 + (t & 3) * 8;
    const unsigned short* b_src = Bt + (size_t)(n0 + (t >> 2)) * 512 + (t & 3) * 8;

// A: 2 loads/thread, ring mod 3 (16KB each)
#define STAGE_A(kt) do { \
    unsigned short* dst_ = ldsb + ((kt) % 3) * 8192; \
    const int ko_ = (kt) * 32; \
    gload_lds16(a_src + ko_, dst_ + t * 8); \
    gload_lds16(a_src + 65536 + ko_, dst_ + 4096 + t * 8); \
} while (0)

// B: 1 load/thread, ring mod 4 (8KB each)
#define STAGE_B(kt) do { \
    unsigned short* dst_ = ldsb + 24576 + ((kt) % 4) * 4096; \
    gload_lds16(b_src + (kt) * 32, dst_ + t * 8); \
} while (0)

// One K-step, ONE barrier. wait(stage(kt) landed) -> barrier -> issue A(kt+2),B(kt+3) -> compute(kt).
#define KSTEP(kt, SA, SB, VMSTR) do { \
    asm volatile("s_waitcnt vmcnt(" VMSTR ")" ::: "memory"); \
    __builtin_amdgcn_s_barrier(); \
    __builtin_amdgcn_sched_barrier(0); \
    if (SA) STAGE_A((kt) + 2); \
    if (SB) STAGE_B((kt) + 3); \
    const char* abase_ = (const char*)(ldsb + ((kt) % 3) * 8192); \
    const char* bbase_ = (const char*)(ldsb + 24576 + ((kt) % 4) * 4096); \
    bf16x8 af_[4], bfv_[4]; \
    _Pragma("unroll") \
    for (int f_ = 0; f_ < 4; ++f_) \
        af_[f_] = *(const bf16x8*)(abase_ + (wr * 64 + f_ * 16 + rl) * 64 + soff); \
    _Pragma("unroll") \
    for (int j_ = 0; j_ < 4; ++j_) \
        bfv_[j_] = *(const bf16x8*)(bbase_ + (wcn * 64 + j_ * 16 + rl) * 64 + soff); \
    __builtin_amdgcn_s_setprio(1); \
    _Pragma("unroll") \
    for (int fm_ = 0; fm_ < 4; ++fm_) \
        _Pragma("unroll") \
        for (int j_ = 0; j_ < 4; ++j_) \
            acc[fm_][j_] = __builtin_amdgcn_mfma_f32_16x16x32_bf16( \
                af_[fm_], bfv_[j_], acc[fm_][j_], 0, 0, 0); \
    __builtin_amdgcn_s_setprio(0); \
    __builtin_amdgcn_sched_barrier(0); \
} while (0)

    // prologue in steady-state FIFO order: B0 | A0,B1 | A1,B2
    STAGE_B(0); STAGE_A(0); STAGE_B(1); STAGE_A(1); STAGE_B(2);
    KSTEP(0, 1, 1, "4");  KSTEP(1, 1, 1, "4");  KSTEP(2, 1, 1, "4");  KSTEP(3, 1, 1, "4");
    KSTEP(4, 1, 1, "4");  KSTEP(5, 1, 1, "4");  KSTEP(6, 1, 1, "4");  KSTEP(7, 1, 1, "4");
    KSTEP(8, 1, 1, "4");  KSTEP(9, 1, 1, "4");  KSTEP(10, 1, 1, "4"); KSTEP(11, 1, 1, "4");
    KSTEP(12, 1, 1, "4"); KSTEP(13, 1, 0, "4"); KSTEP(14, 0, 0, "3"); KSTEP(15, 0, 0, "0");
#undef STAGE_A
#undef STAGE_B
#undef KSTEP

    // ---- epilogue: 4 passes of 64 rows; stem loads issued EARLY (T14), wC (L2) inline ----
    float* cs = (float*)ldsb;
    const int erow = t >> 5;                       // 0..15
    const int ecol = (t & 31) * 4;                 // 32 lanes x 16B = full 512B row
    #pragma unroll
    for (int sb = 0; sb < 4; ++sb) {
        f32x4 sv[4];
        #pragma unroll
        for (int i2 = 0; i2 < 4; ++i2) {
            int b = m0 + sb * 64 + i2 * 16 + erow;
            sv[i2] = *(const f32x4*)&stem[(size_t)b * 65536 + (size_t)n0 + ecol];
        }
        __syncthreads();   // K-loop LDS done (sb=0) / previous pass cs reads done (sb>0)
        if (wr == sb) {
            #pragma unroll
            for (int fm = 0; fm < 4; ++fm) {
                #pragma unroll
                for (int n = 0; n < 4; ++n) {
                    int c = wcn * 64 + n * 16 + rl;
                    #pragma unroll
                    for (int i = 0; i < 4; ++i)
                        cs[(fm * 16 + q * 4 + i) * 132 + c] = acc[fm][n][i];
                }
            }
        }
        __syncthreads();
        #pragma unroll
        for (int i2 = 0; i2 < 4; ++i2) {
            int row = i2 * 16 + erow;
            int b = m0 + sb * 64 + row;
            size_t gb = (size_t)b * 65536 + (size_t)n0 + ecol;
            f32x4 cv = *(const f32x4*)&cs[row * 132 + ecol];
            f32x4 wv = *(const f32x4*)&wC[((size_t)b << 8) + (n0 & 255) + ecol];
            f32x4 ov;
            #pragma unroll
            for (int jj = 0; jj < 4; ++jj)
                ov[jj] = sv[i2][jj] + (cv[jj] - sv[i2][jj]) * wv[jj];
            *(f32x4*)&out[gb] = ov;
        }
    }
}

// ---------- Kernel C (fallback, ws too small): in-kernel convert+transpose, 128^2 ----------
__global__ void gemm_fb(const unsigned short* __restrict__ attn_sw,
                        const float* __restrict__ vocab,
                        const float* __restrict__ stem,
                        const float* __restrict__ wC,
                        float* __restrict__ out) {
    const int tile_m = blockIdx.x & 7;
    const int tile_n = blockIdx.x >> 3;
    const int m0 = tile_m << 7;
    const int n0 = tile_n << 7;
    const int t = threadIdx.x;
    const int lane = t & 63;
    const int wv = t >> 6;
    const int wm = wv >> 1, wn = wv & 1;

    __shared__ unsigned short Asl[128 * 32];
    __shared__ unsigned short Bsl[128 * 32];

    f32x4 acc[4][4];
    const f32x4 z = {0.f, 0.f, 0.f, 0.f};
    #pragma unroll
    for (int i = 0; i < 4; ++i)
        #pragma unroll
        for (int j = 0; j < 4; ++j) acc[i][j] = z;

    const unsigned short* a_base = attn_sw + ((size_t)m0 << 9);
    const int q = lane >> 4;
    const int rl = lane & 15;

    for (int ks = 0; ks < 16; ++ks) {
        #pragma unroll
        for (int it = 0; it < 2; ++it) {
            int idx = it * 256 + t;
            int r = idx >> 2, blk = idx & 3;
            gload_lds16(a_base + r * 512 + ks * 32 + blk * 8, Asl + idx * 8);
        }
        #pragma unroll
        for (int it = 0; it < 2; ++it) {
            int lin = it * 256 + t;
            int pair = lin >> 5;
            int chunk = lin & 31;
            int k = pair * 2;
            const float* g0 = vocab + (size_t)(ks * 32 + k) * 65536 + n0 + chunk * 4;
            float4 v0 = *(const float4*)g0;
            float4 v1 = *(const float4*)(g0 + 65536);
            #pragma unroll
            for (int j = 0; j < 4; ++j) {
                int n = chunk * 4 + j;
                unsigned d = (unsigned)f2bf((&v0.x)[j]) | ((unsigned)f2bf((&v1.x)[j]) << 16);
                int ae = n * 32 + ((((k >> 3) ^ ((n >> 2) & 3))) << 3) + (k & 7);
                *(unsigned*)((char*)Bsl + ae * 2) = d;
            }
        }
        __syncthreads();
        bf16x8 af[4], bfr[4];
        #pragma unroll
        for (int f = 0; f < 4; ++f) {
            int r = wm * 64 + f * 16 + rl;
            af[f] = *(const bf16x8*)((const char*)Asl + r * 64 + ((q ^ ((r >> 2) & 3)) << 4));
            int c = wn * 64 + f * 16 + rl;
            bfr[f] = *(const bf16x8*)((const char*)Bsl + c * 64 + ((q ^ ((c >> 2) & 3)) << 4));
        }
        __syncthreads();
        #pragma unroll
        for (int fm = 0; fm < 4; ++fm)
            #pragma unroll
            for (int fn = 0; fn < 4; ++fn)
                acc[fm][fn] = __builtin_amdgcn_mfma_f32_16x16x32_bf16(af[fm], bfr[fn], acc[fm][fn], 0, 0, 0);
    }

    #pragma unroll
    for (int fm = 0; fm < 4; ++fm) {
        int rbase = m0 + wm * 64 + fm * 16 + ((lane >> 4) << 2);
        #pragma unroll
        for (int fn = 0; fn < 4; ++fn) {
            int c = n0 + wn * 64 + fn * 16 + (lane & 15);
            #pragma unroll
            for (int i = 0; i < 4; ++i) {
                int b = rbase + i;
                float w = wC[(b << 8) + (c & 255)];
                size_t o = ((size_t)b << 16) + (size_t)c;
                float sv = stem[o];
                out[o] = sv + (acc[fm][fn][i] - sv) * w;
            }
        }
    }
}

// Fallback producers (only used when ws too small for Bt)
__global__ void attn_kernel(const float* __restrict__ morphosyn,
                            const float* __restrict__ W,
                            unsigned short* __restrict__ attn_sw) {
    const int b = blockIdx.x;
    const int t = threadIdx.x;
    __shared__ float ms[128];
    __shared__ float red[4];
    if (t < 128) ms[t] = morphosyn[b * 128 + t];
    __syncthreads();
    float acc0 = 0.f, acc1 = 0.f;
    #pragma unroll 8
    for (int dm = 0; dm < 128; ++dm) {
        float m = ms[dm];
        acc0 = fmaf(m, W[dm * 512 + t], acc0);
        acc1 = fmaf(m, W[dm * 512 + t + 256], acc1);
    }
    const int lane = t & 63, wid = t >> 6;
    float mx = fmaxf(acc0, acc1);
    #pragma unroll
    for (int o = 32; o; o >>= 1) mx = fmaxf(mx, __shfl_xor(mx, o));
    if (lane == 0) red[wid] = mx;
    __syncthreads();
    mx = fmaxf(fmaxf(red[0], red[1]), fmaxf(red[2], red[3]));
    __syncthreads();
    float e0 = __expf(acc0 - mx), e1 = __expf(acc1 - mx);
    float sm = e0 + e1;
    #pragma unroll
    for (int o = 32; o; o >>= 1) sm += __shfl_xor(sm, o);
    if (lane == 0) red[wid] = sm;
    __syncthreads();
    sm = red[0] + red[1] + red[2] + red[3];
    const float inv = 1.0f / sm;
    const int swz = (b >> 2) & 3;
    #pragma unroll
    for (int h = 0; h < 2; ++h) {
        int v = t + h * 256;
        int ae = (v >> 5) * 32 + ((((v >> 3) & 3) ^ swz) << 3) + (v & 7);
        attn_sw[b * 512 + ae] = f2bf((h ? e1 : e0) * inv);
    }
}

__global__ void wc_kernel(const float* __restrict__ logits,
                          const float* __restrict__ alpha,
                          const float* __restrict__ beta,
                          const float* __restrict__ phi,
                          float* __restrict__ wC) {
    const int b = blockIdx.x;
    const int t = threadIdx.x;
    const int lane = t & 63, wid = t >> 6;
    __shared__ float part[4][256];
    __shared__ float wsum[4];
    float a0 = alpha[0], a1 = alpha[1];
    float am = fmaxf(a0, a1);
    float ea0 = __expf(a0 - am), ea1 = __expf(a1 - am);
    float as = ea0 + ea1;
    float b0 = beta[0], b1 = beta[1];
    float bm = fmaxf(b0, b1);
    float eb0 = __expf(b0 - bm), eb1 = __expf(b1 - bm);
    float bs = eb0 + eb1;
    float p[5];
    float pm = -1e30f;
    #pragma unroll
    for (int k = 0; k < 5; ++k) { p[k] = phi[k]; pm = fmaxf(pm, p[k]); }
    float ps = 0.f;
    #pragma unroll
    for (int k = 0; k < 5; ++k) { p[k] = __expf(p[k] - pm); ps += p[k]; }
    const float wa[2] = {ea0 / as, ea1 / as}, wb[2] = {eb0 / bs, eb1 / bs};
    f32x4 accv = {0.f, 0.f, 0.f, 0.f};
    #pragma unroll
    for (int s5 = 0; s5 < 5; ++s5) {
        int sl = wid * 5 + s5;
        int i = sl >= 10;
        int j = (sl / 5) & 1;
        int k = sl - (sl / 5) * 5;
        const float* base = logits + ((size_t)(((i * 2 + j) * 1024 + b) * 5 + k)) * 256;
        f32x4 x = *(const f32x4*)(base + lane * 4);
        float mx = fmaxf(fmaxf(x[0], x[1]), fmaxf(x[2], x[3]));
        #pragma unroll
        for (int o = 32; o; o >>= 1) mx = fmaxf(mx, __shfl_xor(mx, o));
        f32x4 e;
        float sm = 0.f;
        #pragma unroll
        for (int r = 0; r < 4; ++r) { e[r] = __expf(x[r] - mx); sm += e[r]; }
        #pragma unroll
        for (int o = 32; o; o >>= 1) sm += __shfl_xor(sm, o);
        float w = wa[i] * wb[j] * (p[k] / ps) / sm;
        #pragma unroll
        for (int r = 0; r < 4; ++r) accv[r] += w * e[r];
    }
    *(f32x4*)&part[wid][lane * 4] = accv;
    __syncthreads();
    float v = part[0][t] + part[1][t] + part[2][t] + part[3][t];
    #pragma unroll
    for (int o = 1; o < 64; o <<= 1) {
        float u = __shfl_up(v, o);
        if (lane >= o) v += u;
    }
    if (lane == 63) wsum[wid] = v;
    __syncthreads();
    float offv = 0.f;
    for (int w2 = 0; w2 < wid; ++w2) offv += wsum[w2];
    wC[b * 256 + t] = v + offv;
}

extern "C" void kernel_launch(void* const* d_in, const int* in_sizes, int n_in,
                              void* d_out, int out_size, void* d_ws, size_t ws_size,
                              hipStream_t stream) {
    const float* stem    = (const float*)d_in[0];
    const float* morpho  = (const float*)d_in[1];
    const float* logits  = (const float*)d_in[2];
    const float* W       = (const float*)d_in[3];
    const float* vocab   = (const float*)d_in[4];
    const float* alpha   = (const float*)d_in[5];
    const float* beta    = (const float*)d_in[6];
    const float* phi     = (const float*)d_in[7];
    float* out = (float*)d_out;

    unsigned short* attn_sw = (unsigned short*)d_ws;                 // 1 MB
    float* wC = (float*)((char*)d_ws + (1 << 20));                   // 1 MB
    unsigned short* Bt = (unsigned short*)((char*)d_ws + (2 << 20)); // 64 MB

    const size_t need = (size_t)(2 << 20) + (size_t)64 * 1024 * 1024;

    if (ws_size >= need) {
        prepass_kernel<<<4096, 256, 0, stream>>>(vocab, Bt, logits, alpha, beta, phi, wC,
                                                 morpho, W, attn_sw);
        gemm_kernel<<<2048, 512, 0, stream>>>(attn_sw, Bt, stem, wC, out);
    } else {
        attn_kernel<<<1024, 256, 0, stream>>>(morpho, W, attn_sw);
        wc_kernel<<<1024, 256, 0, stream>>>(logits, alpha, beta, phi, wC);
        gemm_fb<<<4096, 256, 0, stream>>>(attn_sw, vocab, stem, wC, out);
    }
}